// Round 3
// baseline (566.754 us; speedup 1.0000x reference)
//
#include <hip/hip_runtime.h>

// Attention_884763263569 on gfx950 — v3.
// x:[65536,3,512] f32, Wk/Wv:[32,512], Wq:[32,1536], Wfc:[10,32], bfc:[10] -> out [65536,10] f32.
//
// Folding: out = sum_t a_t * (Wfc@Wv @ x_t) + bfc  ->  Wvf = Wfc@Wv [10,512].
// Weights in global in MFMA-fragment order [t][kc][n][lane][8] (fp16) -> B-loads are base+lane*16.
// v3: M=16 samples/wave (acc 60 VGPR), __launch_bounds__(256,4) for 4 waves/SIMD,
// depth-1 register prefetch of the x stream (B loads issued first so MFMA vmcnt
// waits don't drain the prefetch). Zero LDS, zero barriers.

typedef __attribute__((ext_vector_type(4))) float  f32x4;
typedef __attribute__((ext_vector_type(8))) _Float16 h16x8;

#define T_VIEWS 3
#define D_DIM   512
#define P_DIM   32
#define C_DIM   10
#define NROWS   80          // padded logical rows per t
#define NT      5           // n-tiles of 16
#define KC      16          // k-chunks of 32
#define M_WAVE  16
#define WAVES_PER_BLOCK 4
#define SAMPLES_PER_BLOCK (M_WAVE*WAVES_PER_BLOCK)   // 64

// ---------------- Kernel A: build fragment-ordered fp16 weights in d_ws ----------------
// Logical (t, j, d) -> frag addr (((t*KC+kc)*NT+n)*64 + quad*16+col)*8 + jj
__global__ void build_weights(const float* __restrict__ Wk,
                              const float* __restrict__ Wv,
                              const float* __restrict__ Wq,
                              const float* __restrict__ Wfc,
                              _Float16* __restrict__ Wf) {
    const int row = blockIdx.x;          // 0 .. 3*80-1
    const int t   = row / NROWS;
    const int j   = row % NROWS;
    const int d   = threadIdx.x;         // 0..511
    float val;
    if (j < 32) {
        val = Wk[j * D_DIM + d];
    } else if (j < 64) {
        const int p = j - 32;
        val = Wq[p * (T_VIEWS * D_DIM) + t * D_DIM + d];
    } else if (j < 64 + C_DIM) {
        const int i = j - 64;
        float s = 0.f;
        #pragma unroll
        for (int p = 0; p < P_DIM; ++p)
            s += Wfc[i * P_DIM + p] * Wv[p * D_DIM + d];
        val = s;
    } else {
        val = 0.f;                        // pad rows (d_ws is poisoned -> must zero)
    }
    const int n = j >> 4, col = j & 15;
    const int kc = d >> 5, r = d & 31, quad = r >> 3, jj = r & 7;
    const size_t addr = (size_t)((((t * KC + kc) * NT + n) * 64) + quad * 16 + col) * 8 + jj;
    Wf[addr] = (_Float16)val;
}

// ---------------- Main fused kernel ----------------
__global__ __launch_bounds__(256, 4) void attn_fused(
        const float* __restrict__ x,
        const _Float16* __restrict__ Wf,
        const float* __restrict__ bfc,
        float* __restrict__ out) {
    const int lane = threadIdx.x & 63;
    const int wave = threadIdx.x >> 6;
    const int col  = lane & 15;          // MFMA: A-row m / B-col n / C-col
    const int quad = lane >> 4;          // MFMA: k-group / C row-group
    const int row_base = blockIdx.x * SAMPLES_PER_BLOCK + wave * M_WAVE;

    // acc[t][n]: n 0,1 = k_t ; 2,3 = q-part_t ; 4 = y_t (rows 0..9) + pad
    f32x4 acc[3][NT];
    #pragma unroll
    for (int t = 0; t < 3; ++t)
        #pragma unroll
        for (int n = 0; n < NT; ++n)
            acc[t][n] = (f32x4)0.f;

    // A-operand: lane (col,quad) holds x[m=col][k = quad*8 + j].
    // x rows are [3,512] contiguous -> address is linear in (t,kc): += 32 floats/iter.
    const float* xp = x + (size_t)(row_base + col) * (T_VIEWS * D_DIM) + quad * 8;
    const _Float16* wp = Wf + lane * 8;

    // prime the x pipeline (depth-1)
    f32x4 x0 = __builtin_nontemporal_load((const f32x4*)xp);
    f32x4 x1 = __builtin_nontemporal_load((const f32x4*)(xp + 4));

    #pragma unroll
    for (int t = 0; t < 3; ++t) {
        #pragma unroll 2
        for (int kc = 0; kc < KC; ++kc) {
            // B first (L2-resident), so MFMA's vmcnt wait leaves the x prefetch in flight
            h16x8 b[NT];
            #pragma unroll
            for (int n = 0; n < NT; ++n)
                b[n] = *(const h16x8*)(wp + n * 512);
            // prefetch next x (last iteration re-reads current addr: valid, discarded)
            const float* xn = xp + ((t == 2) ? (kc < KC - 1 ? 32 : 0) : 32);
            const f32x4 x0n = __builtin_nontemporal_load((const f32x4*)xn);
            const f32x4 x1n = __builtin_nontemporal_load((const f32x4*)(xn + 4));
            // convert current x to fp16 A-fragment
            h16x8 a;
            #pragma unroll
            for (int i = 0; i < 4; ++i) {
                a[i]     = (_Float16)x0[i];
                a[i + 4] = (_Float16)x1[i];
            }
            #pragma unroll
            for (int n = 0; n < NT; ++n)
                acc[t][n] = __builtin_amdgcn_mfma_f32_16x16x32_f16(a, b[n], acc[t][n], 0, 0, 0);
            x0 = x0n; x1 = x1n;
            xp += 32;
            wp += NT * 512;
        }
    }

    // ---------------- Epilogue (registers + shfl only) ----------------
    // C layout: element r holds row (quad*4 + r), column (n*16 + col).
    const float bias = (col < C_DIM) ? bfc[col] : 0.f;

    float outv[4];
    #pragma unroll
    for (int r = 0; r < 4; ++r) {
        const float qa = acc[0][2][r] + acc[1][2][r] + acc[2][2][r];
        const float qb = acc[0][3][r] + acc[1][3][r] + acc[2][3][r];
        float s0 = qa * acc[0][0][r] + qb * acc[0][1][r];
        float s1 = qa * acc[1][0][r] + qb * acc[1][1][r];
        float s2 = qa * acc[2][0][r] + qb * acc[2][1][r];
        #pragma unroll
        for (int msk = 1; msk <= 8; msk <<= 1) {
            s0 += __shfl_xor(s0, msk, 64);
            s1 += __shfl_xor(s1, msk, 64);
            s2 += __shfl_xor(s2, msk, 64);
        }
        const float mx = fmaxf(s0, fmaxf(s1, s2));
        const float e0 = __expf(s0 - mx);
        const float e1 = __expf(s1 - mx);
        const float e2 = __expf(s2 - mx);
        const float inv = 1.f / (e0 + e1 + e2);
        outv[r] = (e0 * acc[0][4][r] + e1 * acc[1][4][r] + e2 * acc[2][4][r]) * inv + bias;
    }

    if (col < C_DIM) {
        const int b0 = row_base + quad * 4;
        #pragma unroll
        for (int r = 0; r < 4; ++r)
            out[(size_t)(b0 + r) * C_DIM + col] = outv[r];
    }
}

extern "C" void kernel_launch(void* const* d_in, const int* in_sizes, int n_in,
                              void* d_out, int out_size, void* d_ws, size_t ws_size,
                              hipStream_t stream) {
    const float* x   = (const float*)d_in[0];
    const float* Wk  = (const float*)d_in[1];
    const float* Wv  = (const float*)d_in[2];
    const float* Wq  = (const float*)d_in[3];
    const float* Wfc = (const float*)d_in[4];
    const float* bfc = (const float*)d_in[5];
    _Float16* Wf = (_Float16*)d_ws;       // 3*80*512 halfs = 240 KB, fragment-ordered

    hipLaunchKernelGGL(build_weights, dim3(T_VIEWS * NROWS), dim3(D_DIM), 0, stream,
                       Wk, Wv, Wq, Wfc, Wf);

    const int B_TOTAL = in_sizes[0] / (T_VIEWS * D_DIM);      // 65536
    const int blocks = B_TOTAL / SAMPLES_PER_BLOCK;           // 1024
    hipLaunchKernelGGL(attn_fused, dim3(blocks), dim3(256), 0, stream,
                       x, Wf, bfc, (float*)d_out);
}